// Round 5
// baseline (588.979 us; speedup 1.0000x reference)
//
#include <hip/hip_runtime.h>

typedef __attribute__((ext_vector_type(8))) short short8;
typedef __attribute__((ext_vector_type(4))) float f32x4;
typedef unsigned short ushort_t;
typedef unsigned int u32;
typedef unsigned long long u64;

#define MFMA16(a,b,c) __builtin_amdgcn_mfma_f32_16x16x32_bf16((a),(b),(c),0,0,0)

__device__ __forceinline__ ushort_t f2bf(float f){
  union { float f; u32 u; } v; v.f = f;
  u32 r = v.u + 0x7fffu + ((v.u >> 16) & 1u);
  return (ushort_t)(r >> 16);
}
__device__ __forceinline__ float bf2f(ushort_t h){
  union { u32 u; float f; } v; v.u = ((u32)h) << 16; return v.f;
}
__device__ __forceinline__ u64 pack4(float a, float b, float c, float d){
  u32 p0 = (u32)f2bf(a) | ((u32)f2bf(b) << 16);
  u32 p1 = (u32)f2bf(c) | ((u32)f2bf(d) << 16);
  return (u64)p0 | ((u64)p1 << 32);
}
__device__ __forceinline__ u32 pack2(float a, float b){
  return (u32)f2bf(a) | ((u32)f2bf(b) << 16);
}
// force-materialize a loaded fragment at this program point (defeats load sinking)
__device__ __forceinline__ void pin(short8 &v){ asm volatile("" : "+v"(v)); }

template<int CTRL>
__device__ __forceinline__ float dpp_add(float x){
  union { float f; int i; } a, b;
  a.f = x;
  b.i = __builtin_amdgcn_update_dpp(a.i, a.i, CTRL, 0xF, 0xF, false);
  return x + b.f;
}
// 4-lane reduce (xor1, xor2 within quads)
__device__ __forceinline__ float red4_add(float x){
  x = dpp_add<0xB1>(x); x = dpp_add<0x4E>(x);
  return x;
}

// B=4096 T=32 C=180 H=6 HD=30 ; tokens=131072
// ws (ushort): wqkv[6][3][32][192] | w1t[768][192] | w2t[192][768]
#define WQKV_ELEMS (576*192)
#define W1T_ELEMS  (768*192)
#define W2T_ELEMS  (192*768)

#define SH 200   // 400B rows (192 cols + pad); word-stride 100 -> 2-way max on b128
#define SS 40    //  80B rows: attn scratch
#define SA 184   // att rows [t][c] c=head*30+d (180 cols + 4 pad); 368B rows

__global__ void prep_weights(const float* __restrict__ wq, const float* __restrict__ wk,
                             const float* __restrict__ wv, const float* __restrict__ w1,
                             const float* __restrict__ w2, ushort_t* __restrict__ ws){
  ushort_t* wqkv = ws;
  ushort_t* w1t = ws + WQKV_ELEMS;
  ushort_t* w2t = w1t + W1T_ELEMS;
  int tid = blockIdx.x * blockDim.x + threadIdx.x;
  int stride = gridDim.x * blockDim.x;
  for (int i = tid; i < WQKV_ELEMS; i += stride){
    int k = i % 192; int row = i / 192;
    int d = row & 31; int m = (row >> 5) % 3; int h = row / 96;
    float v = 0.f;
    if (d < 30 && k < 180){
      const float* W = (m == 0) ? wq : ((m == 1) ? wk : wv);
      v = W[(h*180 + k)*30 + d];
    }
    wqkv[i] = f2bf(v);
  }
  for (int i = tid; i < W1T_ELEMS; i += stride){
    int c = i % 192; int n = i / 192;
    float v = (n < 720 && c < 180) ? w1[c*720 + n] : 0.f;
    w1t[i] = f2bf(v);
  }
  for (int i = tid; i < W2T_ELEMS; i += stride){
    int c4 = i % 768; int n = i / 768;
    float v = (n < 180 && c4 < 720) ? w2[c4*180 + n] : 0.f;
    w2t[i] = f2bf(v);
  }
}

// ---------------- Fused kernel: 32 tokens (1 batch)/block, 4 waves, 45KB LDS
// -> 3 blocks/CU (12 waves/CU). Regions:
//   W   (20.5KB): per-wave attn scratch -> act chunk (12.8KB)
//   hn  (12.8KB): LN1 out -> x2 bf16 -> LN2 out
//   att (11.8KB): attn out [t][c] vector-readable
// x2 fp32 -> out (global, coalesced); MLP epilogue RMWs out.
__global__ __launch_bounds__(256, 3)
void block_kernel(const float* __restrict__ x,
                  const float* __restrict__ g1, const float* __restrict__ be1,
                  const float* __restrict__ g2, const float* __restrict__ be2,
                  const float* __restrict__ b1, const float* __restrict__ b2,
                  const ushort_t* __restrict__ wqkv, const ushort_t* __restrict__ w1t,
                  const ushort_t* __restrict__ w2t, float* __restrict__ out){
  __shared__ __align__(16) ushort_t W[4*2*32*SS];   // 10240 ushorts
  __shared__ __align__(16) ushort_t hn[32*SH];      // 6400
  __shared__ __align__(16) ushort_t att[32*SA];     // 5888

  int tid = threadIdx.x;
  int wave = tid >> 6, lane = tid & 63;
  int quad = lane >> 4, c16 = lane & 15;
  long base = (long)blockIdx.x * 5760;   // 32 tokens * 180

  // ---- LN1 straight from global: 8 threads/row, 24 cols each
  {
    int row = tid >> 3, sub = tid & 7;
    int c0 = sub*24;
    f32x4 xv[6];
    float s1 = 0.f, s2 = 0.f;
    #pragma unroll
    for (int gi = 0; gi < 6; gi++){
      int c = c0 + gi*4;
      if (c < 180) xv[gi] = *(const f32x4*)(x + base + (long)row*180 + c);
      else         xv[gi] = (f32x4)0.f;
      s1 += xv[gi].x + xv[gi].y + xv[gi].z + xv[gi].w;
      s2 += xv[gi].x*xv[gi].x + xv[gi].y*xv[gi].y + xv[gi].z*xv[gi].z + xv[gi].w*xv[gi].w;
    }
    s1 = red4_add(s1); s1 += __shfl_xor(s1, 4);
    s2 = red4_add(s2); s2 += __shfl_xor(s2, 4);
    float mu = s1 * (1.f/180.f);
    float rstd = rsqrtf(s2 * (1.f/180.f) - mu*mu + 1e-5f);
    #pragma unroll
    for (int gi = 0; gi < 6; gi++){
      int c = c0 + gi*4;
      if (c < 180){
        f32x4 gg = *(const f32x4*)(g1 + c);
        f32x4 bb = *(const f32x4*)(be1 + c);
        *(u64*)(hn + row*SH + c) = pack4((xv[gi].x - mu)*rstd*gg.x + bb.x,
                                         (xv[gi].y - mu)*rstd*gg.y + bb.y,
                                         (xv[gi].z - mu)*rstd*gg.z + bb.z,
                                         (xv[gi].w - mu)*rstd*gg.w + bb.w);
      } else {
        *(u64*)(hn + row*SH + c) = 0ull;
      }
    }
  }
  __syncthreads();

  // ---- attention: 6 heads; wave w does heads {w, w+4 (if <6)}
  {
    ushort_t* buf0 = W + wave*(2*32*SS);   // q, then vT
    ushort_t* buf1 = buf0 + 32*SS;         // k, then P
    const float scl = 0.18257418583505537f;  // 30^-0.5

    for (int jj = 0; jj < 2; jj++){
      int head = wave + jj*4;
      if (head >= 6) break;
      const ushort_t* wbase = wqkv + head*(96*192);

      // ===== pass 1: Q,K (preload both weight tiles fully, pinned)
      f32x4 accq[2][2], acck[2][2];
      #pragma unroll
      for (int i = 0; i < 2; i++)
        #pragma unroll
        for (int jx = 0; jx < 2; jx++){ accq[i][jx]=(f32x4)0.f; acck[i][jx]=(f32x4)0.f; }
      short8 aqw[2][6], akw[2][6];
      #pragma unroll
      for (int mt = 0; mt < 2; mt++)
        #pragma unroll
        for (int kk = 0; kk < 6; kk++){
          aqw[mt][kk] = *(const short8*)(wbase + (      mt*16 + c16)*192 + kk*32 + quad*8);
          akw[mt][kk] = *(const short8*)(wbase + (32  + mt*16 + c16)*192 + kk*32 + quad*8);
          pin(aqw[mt][kk]); pin(akw[mt][kk]);
        }
      #pragma unroll
      for (int kk = 0; kk < 6; kk++){
        short8 hf[2];
        #pragma unroll
        for (int nt = 0; nt < 2; nt++)
          hf[nt] = *(const short8*)(hn + (nt*16 + c16)*SH + kk*32 + quad*8);
        #pragma unroll
        for (int mt = 0; mt < 2; mt++)
          #pragma unroll
          for (int nt = 0; nt < 2; nt++){
            accq[mt][nt] = MFMA16(aqw[mt][kk], hf[nt], accq[mt][nt]);  // C[d][t] = qT
            acck[mt][nt] = MFMA16(akw[mt][kk], hf[nt], acck[mt][nt]);  // C[d][t] = kT
          }
      }
      // q,k rowmajor [t][d] into scratch
      #pragma unroll
      for (int mt = 0; mt < 2; mt++)
        #pragma unroll
        for (int nt = 0; nt < 2; nt++){
          *(u64*)(buf0 + (nt*16 + c16)*SS + mt*16 + quad*4) =
            pack4(accq[mt][nt][0], accq[mt][nt][1], accq[mt][nt][2], accq[mt][nt][3]);
          *(u64*)(buf1 + (nt*16 + c16)*SS + mt*16 + quad*4) =
            pack4(acck[mt][nt][0], acck[mt][nt][1], acck[mt][nt][2], acck[mt][nt][3]);
        }
      // S^T = MFMA(A=k, B=q): C[s][t]
      f32x4 sacc[2][2];
      #pragma unroll
      for (int i = 0; i < 2; i++){ sacc[i][0]=(f32x4)0.f; sacc[i][1]=(f32x4)0.f; }
      short8 akf[2], bqf[2];
      #pragma unroll
      for (int mt = 0; mt < 2; mt++) akf[mt] = *(const short8*)(buf1 + (mt*16 + c16)*SS + quad*8);
      #pragma unroll
      for (int nt = 0; nt < 2; nt++) bqf[nt] = *(const short8*)(buf0 + (nt*16 + c16)*SS + quad*8);
      #pragma unroll
      for (int mt = 0; mt < 2; mt++)
        #pragma unroll
        for (int nt = 0; nt < 2; nt++)
          sacc[mt][nt] = MFMA16(akf[mt], bqf[nt], sacc[mt][nt]);
      // softmax: lane owns token t=nt*16+c16; reduce over quads (xor16,32)
      #pragma unroll
      for (int nt = 0; nt < 2; nt++){
        int t = nt*16 + c16;
        float v[8];
        #pragma unroll
        for (int r = 0; r < 4; r++){
          int s0 = quad*4 + r, s1v = 16 + quad*4 + r;
          v[r]   = (s0  > t) ? -1e30f : sacc[0][nt][r]*scl;
          v[4+r] = (s1v > t) ? -1e30f : sacc[1][nt][r]*scl;
        }
        float m = v[0];
        #pragma unroll
        for (int i = 1; i < 8; i++) m = fmaxf(m, v[i]);
        m = fmaxf(m, __shfl_xor(m, 16));
        m = fmaxf(m, __shfl_xor(m, 32));
        float e[8], s = 0.f;
        #pragma unroll
        for (int i = 0; i < 8; i++){ e[i] = __expf(v[i] - m); s += e[i]; }
        s += __shfl_xor(s, 16);
        s += __shfl_xor(s, 32);
        float inv = 1.f / s;
        *(u64*)(buf1 + t*SS +      quad*4) = pack4(e[0]*inv, e[1]*inv, e[2]*inv, e[3]*inv);
        *(u64*)(buf1 + t*SS + 16 + quad*4) = pack4(e[4]*inv, e[5]*inv, e[6]*inv, e[7]*inv);
      }
      // ===== pass 2: V (own weight preload; q scratch dead -> vT into buf0)
      f32x4 accv[2][2];
      #pragma unroll
      for (int i = 0; i < 2; i++){ accv[i][0]=(f32x4)0.f; accv[i][1]=(f32x4)0.f; }
      short8 avw[2][6];
      #pragma unroll
      for (int nt = 0; nt < 2; nt++)
        #pragma unroll
        for (int kk = 0; kk < 6; kk++){
          avw[nt][kk] = *(const short8*)(wbase + (64 + nt*16 + c16)*192 + kk*32 + quad*8);
          pin(avw[nt][kk]);
        }
      #pragma unroll
      for (int kk = 0; kk < 6; kk++){
        short8 hf[2];
        #pragma unroll
        for (int mt = 0; mt < 2; mt++)
          hf[mt] = *(const short8*)(hn + (mt*16 + c16)*SH + kk*32 + quad*8);
        #pragma unroll
        for (int mt = 0; mt < 2; mt++)
          #pragma unroll
          for (int nt = 0; nt < 2; nt++)
            accv[mt][nt] = MFMA16(hf[mt], avw[nt][kk], accv[mt][nt]);  // C[t][d] = v
      }
      // vT [d][t] into buf0
      #pragma unroll
      for (int mt = 0; mt < 2; mt++)
        #pragma unroll
        for (int nt = 0; nt < 2; nt++)
          *(u64*)(buf0 + (nt*16 + c16)*SS + mt*16 + quad*4) =
            pack4(accv[mt][nt][0], accv[mt][nt][1], accv[mt][nt][2], accv[mt][nt][3]);
      // PV: C[d][t] = MFMA(A=vT, B=P) -> att[t][head*30+d] as u32 pairs
      f32x4 oacc[2][2];
      #pragma unroll
      for (int i = 0; i < 2; i++){ oacc[i][0]=(f32x4)0.f; oacc[i][1]=(f32x4)0.f; }
      short8 avf[2], bpf[2];
      #pragma unroll
      for (int mt = 0; mt < 2; mt++) avf[mt] = *(const short8*)(buf0 + (mt*16 + c16)*SS + quad*8);
      #pragma unroll
      for (int nt = 0; nt < 2; nt++) bpf[nt] = *(const short8*)(buf1 + (nt*16 + c16)*SS + quad*8);
      #pragma unroll
      for (int mt = 0; mt < 2; mt++)
        #pragma unroll
        for (int nt = 0; nt < 2; nt++)
          oacc[mt][nt] = MFMA16(avf[mt], bpf[nt], oacc[mt][nt]);
      // write: lane holds d = mt*16 + quad*4 + r (r=0..3) for token t=nt*16+c16
      #pragma unroll
      for (int mt = 0; mt < 2; mt++)
        #pragma unroll
        for (int nt = 0; nt < 2; nt++){
          int t = nt*16 + c16;
          int c = head*30 + mt*16 + quad*4;    // even -> 4B aligned
          ushort_t* p = att + t*SA + c;
          if (mt == 0 || quad < 3){
            *(u32*)(p    ) = pack2(oacc[mt][nt][0], oacc[mt][nt][1]);
            *(u32*)(p + 2) = pack2(oacc[mt][nt][2], oacc[mt][nt][3]);
          } else {
            *(u32*)(p    ) = pack2(oacc[mt][nt][0], oacc[mt][nt][1]);  // d=28,29 only
          }
        }
    }
  }
  __syncthreads();

  // ---- x2 = x + att: fp32 -> out (coalesced), bf16 -> hn ; att read as aligned u64
  #pragma unroll
  for (int it = 0; it < 6; it++){
    int idx = it*256 + tid;
    if (idx < 1440){
      f32x4 v = *(const f32x4*)(x + base + (long)idx*4);
      int row = (int)(((u32)idx * 745655u) >> 25);   // idx/45
      int col4 = (idx - row*45)*4;
      u64 m = *(const u64*)(att + row*SA + col4);
      v.x += bf2f((ushort_t)(m      ));
      v.y += bf2f((ushort_t)(m >> 16));
      v.z += bf2f((ushort_t)(m >> 32));
      v.w += bf2f((ushort_t)(m >> 48));
      *(f32x4*)(out + base + (long)idx*4) = v;                 // x2 fp32
      *(u64*)(hn + row*SH + col4) = pack4(v.x, v.y, v.z, v.w); // x2 bf16
    } else {
      int p = idx - 1440;                 // [0,96): pad cols 180..191
      int row = (p*21846) >> 16;          // p/3
      int g = p - row*3;
      *(u64*)(hn + row*SH + 180 + g*4) = 0ull;
    }
  }
  __syncthreads();

  // ---- LN2 in-place on hn: 8 threads/row, 24 cols each
  {
    int row = tid >> 3, sub = tid & 7;
    int c0 = sub*24;
    float s1 = 0.f, s2 = 0.f;
    u64 mv[6];
    #pragma unroll
    for (int gi = 0; gi < 6; gi++){
      mv[gi] = *(const u64*)(hn + row*SH + c0 + gi*4);
      #pragma unroll
      for (int e = 0; e < 4; e++){
        float v = bf2f((ushort_t)(mv[gi] >> (16*e)));
        s1 += v; s2 += v*v;
      }
    }
    s1 = red4_add(s1); s1 += __shfl_xor(s1, 4);
    s2 = red4_add(s2); s2 += __shfl_xor(s2, 4);
    float mu = s1 * (1.f/180.f);
    float rstd = rsqrtf(s2 * (1.f/180.f) - mu*mu + 1e-5f);
    #pragma unroll
    for (int gi = 0; gi < 6; gi++){
      int c = c0 + gi*4;
      if (c < 180){
        f32x4 gg = *(const f32x4*)(g2 + c);
        f32x4 bb = *(const f32x4*)(be2 + c);
        float v0 = (bf2f((ushort_t)(mv[gi]    )) - mu)*rstd*gg.x + bb.x;
        float v1 = (bf2f((ushort_t)(mv[gi]>>16)) - mu)*rstd*gg.y + bb.y;
        float v2 = (bf2f((ushort_t)(mv[gi]>>32)) - mu)*rstd*gg.z + bb.z;
        float v3 = (bf2f((ushort_t)(mv[gi]>>48)) - mu)*rstd*gg.w + bb.w;
        *(u64*)(hn + row*SH + c) = pack4(v0, v1, v2, v3);
      }
    }
  }
  __syncthreads();

  // ---- MLP: 4 chunks of 192 hidden; act overlays W (attn scratch dead)
  {
    ushort_t* act = W;
    f32x4 outacc[2][3];   // [t-tile][no-tile]
    #pragma unroll
    for (int i = 0; i < 2; i++)
      #pragma unroll
      for (int jx = 0; jx < 3; jx++) outacc[i][jx] = (f32x4)0.f;

    for (int ch = 0; ch < 4; ch++){
      // MLP1: C[n][t] = MFMA(A=w1 rows n, B=hn rows t); w1 fully preloaded, pinned
      f32x4 aacc[3][2];
      #pragma unroll
      for (int i = 0; i < 3; i++)
        #pragma unroll
        for (int jx = 0; jx < 2; jx++) aacc[i][jx] = (f32x4)0.f;
      short8 aw[3][6];
      #pragma unroll
      for (int mi = 0; mi < 3; mi++)
        #pragma unroll
        for (int kk = 0; kk < 6; kk++){
          aw[mi][kk] = *(const short8*)(w1t + (size_t)(ch*192 + (wave*3+mi)*16 + c16)*192 + kk*32 + quad*8);
          pin(aw[mi][kk]);
        }
      #pragma unroll
      for (int kk = 0; kk < 6; kk++){
        short8 bh[2];
        #pragma unroll
        for (int tt = 0; tt < 2; tt++)
          bh[tt] = *(const short8*)(hn + (tt*16 + c16)*SH + kk*32 + quad*8);
        #pragma unroll
        for (int mi = 0; mi < 3; mi++)
          #pragma unroll
          for (int tt = 0; tt < 2; tt++)
            aacc[mi][tt] = MFMA16(aw[mi][kk], bh[tt], aacc[mi][tt]);
      }
      __syncthreads();   // prev chunk's MLP2 done reading act
      // bias + relu + packed store act[t][n]
      #pragma unroll
      for (int mi = 0; mi < 3; mi++){
        int nrel = (wave*3+mi)*16 + quad*4;
        int nabs = ch*192 + nrel;
        f32x4 bias = (f32x4)0.f;
        if (nabs < 720) bias = *(const f32x4*)(b1 + nabs);
        #pragma unroll
        for (int tt = 0; tt < 2; tt++){
          float v0 = fmaxf(aacc[mi][tt][0] + bias[0], 0.f);
          float v1 = fmaxf(aacc[mi][tt][1] + bias[1], 0.f);
          float v2 = fmaxf(aacc[mi][tt][2] + bias[2], 0.f);
          float v3 = fmaxf(aacc[mi][tt][3] + bias[3], 0.f);
          *(u64*)(act + (tt*16 + c16)*SH + nrel) = pack4(v0, v1, v2, v3);
        }
      }
      __syncthreads();   // act ready
      // MLP2: C[t][no] += MFMA(A=act rows t, B=w2 rows no); w2 preloaded, pinned
      short8 bw[3][6];
      #pragma unroll
      for (int ntl = 0; ntl < 3; ntl++)
        #pragma unroll
        for (int kk = 0; kk < 6; kk++){
          bw[ntl][kk] = *(const short8*)(w2t + (size_t)(wave*48 + ntl*16 + c16)*768 + ch*192 + kk*32 + quad*8);
          pin(bw[ntl][kk]);
        }
      #pragma unroll
      for (int kk = 0; kk < 6; kk++){
        short8 aa[2];
        #pragma unroll
        for (int tt = 0; tt < 2; tt++)
          aa[tt] = *(const short8*)(act + (tt*16 + c16)*SH + kk*32 + quad*8);
        #pragma unroll
        for (int tt = 0; tt < 2; tt++)
          #pragma unroll
          for (int ntl = 0; ntl < 3; ntl++)
            outacc[tt][ntl] = MFMA16(aa[tt], bw[ntl][kk], outacc[tt][ntl]);
      }
    }
    // epilogue: out[t][no] = x2 (already in out) + mlp + b2
    #pragma unroll
    for (int ntl = 0; ntl < 3; ntl++){
      int no = wave*48 + ntl*16 + c16;
      if (no < 180){
        float bias = b2[no];
        #pragma unroll
        for (int tt = 0; tt < 2; tt++){
          #pragma unroll
          for (int r = 0; r < 4; r++){
            long a = base + (long)(tt*16 + quad*4 + r)*180 + no;
            out[a] = out[a] + outacc[tt][ntl][r] + bias;
          }
        }
      }
    }
  }
}

extern "C" void kernel_launch(void* const* d_in, const int* in_sizes, int n_in,
                              void* d_out, int out_size, void* d_ws, size_t ws_size,
                              hipStream_t stream) {
  const float* x   = (const float*)d_in[0];
  const float* wq  = (const float*)d_in[1];
  const float* wk  = (const float*)d_in[2];
  const float* wv  = (const float*)d_in[3];
  const float* g1  = (const float*)d_in[4];
  const float* be1 = (const float*)d_in[5];
  const float* g2  = (const float*)d_in[6];
  const float* be2 = (const float*)d_in[7];
  const float* w1  = (const float*)d_in[8];
  const float* b1  = (const float*)d_in[9];
  const float* w2  = (const float*)d_in[10];
  const float* b2  = (const float*)d_in[11];
  ushort_t* ws   = (ushort_t*)d_ws;
  ushort_t* wqkv = ws;
  ushort_t* w1t  = ws + WQKV_ELEMS;
  ushort_t* w2t  = w1t + W1T_ELEMS;
  float* out = (float*)d_out;

  prep_weights<<<512, 256, 0, stream>>>(wq, wk, wv, w1, w2, ws);
  block_kernel<<<4096, 256, 0, stream>>>(x, g1, be1, g2, be2, b1, b2,
                                         wqkv, w1t, w2t, out);
}

// Round 6
// 516.020 us; speedup vs baseline: 1.1414x; 1.1414x over previous
//
#include <hip/hip_runtime.h>

typedef __attribute__((ext_vector_type(8))) short short8;
typedef __attribute__((ext_vector_type(4))) float f32x4;
typedef unsigned short ushort_t;
typedef unsigned int u32;
typedef unsigned long long u64;

#define MFMA16(a,b,c) __builtin_amdgcn_mfma_f32_16x16x32_bf16((a),(b),(c),0,0,0)
#define SBAR() __builtin_amdgcn_sched_barrier(0)

__device__ __forceinline__ ushort_t f2bf(float f){
  union { float f; u32 u; } v; v.f = f;
  u32 r = v.u + 0x7fffu + ((v.u >> 16) & 1u);
  return (ushort_t)(r >> 16);
}
__device__ __forceinline__ float bf2f(ushort_t h){
  union { u32 u; float f; } v; v.u = ((u32)h) << 16; return v.f;
}
__device__ __forceinline__ u64 pack4(float a, float b, float c, float d){
  u32 p0 = (u32)f2bf(a) | ((u32)f2bf(b) << 16);
  u32 p1 = (u32)f2bf(c) | ((u32)f2bf(d) << 16);
  return (u64)p0 | ((u64)p1 << 32);
}
__device__ __forceinline__ u32 pack2(float a, float b){
  return (u32)f2bf(a) | ((u32)f2bf(b) << 16);
}
__device__ __forceinline__ void pin(short8 &v){ asm volatile("" : "+v"(v)); }

template<int CTRL>
__device__ __forceinline__ float dpp_add(float x){
  union { float f; int i; } a, b;
  a.f = x;
  b.i = __builtin_amdgcn_update_dpp(a.i, a.i, CTRL, 0xF, 0xF, false);
  return x + b.f;
}
__device__ __forceinline__ float red4_add(float x){
  x = dpp_add<0xB1>(x); x = dpp_add<0x4E>(x);
  return x;
}

// B=4096 T=32 C=180 H=6 HD=30 ; tokens=131072
// ws (ushort): wqkv[6][3][32][192] | w1t[768][192] | w2t[192][768]
#define WQKV_ELEMS (576*192)
#define W1T_ELEMS  (768*192)
#define W2T_ELEMS  (192*768)

#define SH 200   // 400B rows (192 cols + pad)
#define SS 40    //  80B rows: attn scratch
#define SA 184   // att rows [t][c] c=head*30+d (180 + 4 pad)

// ---- prep: LDS-tiled coalesced transposes (reads coalesced, writes coalesced u32)
// blocks 0..17: wqkv (h=bid/3, m=bid%3) ; 18..29: w1t n-tiles ; 30..41: w2t c4-tiles
__global__ void prep_weights(const float* __restrict__ wq, const float* __restrict__ wk,
                             const float* __restrict__ wv, const float* __restrict__ w1,
                             const float* __restrict__ w2, ushort_t* __restrict__ ws){
  __shared__ float lds_f[11700];
  ushort_t* wqkv = ws;
  ushort_t* w1t = ws + WQKV_ELEMS;
  ushort_t* w2t = w1t + W1T_ELEMS;
  int bid = blockIdx.x, tid = threadIdx.x;

  if (bid < 18){
    int h = bid / 3, m = bid % 3;
    const float* src = ((m == 0) ? wq : (m == 1) ? wk : wv) + (size_t)h*180*30;
    for (int l = 0; l < 22; l++){
      int idx = tid + l*256;
      if (idx < 5400) lds_f[idx] = src[idx];      // [k][d] copy, coalesced
    }
    __syncthreads();
    u32* dst = (u32*)wqkv;
    #pragma unroll
    for (int l = 0; l < 12; l++){
      int j = tid + l*256;           // 3072 u32 = 32 d x 96 kp
      int d = j / 96, kp = j - d*96;
      int k0 = 2*kp;
      float f0 = (d < 30 && k0   < 180) ? lds_f[k0*30 + d]     : 0.f;
      float f1 = (d < 30 && k0+1 < 180) ? lds_f[(k0+1)*30 + d] : 0.f;
      dst[(size_t)(h*96 + m*32 + d)*96 + kp] = pack2(f0, f1);
    }
  } else if (bid < 30){
    int n0 = (bid - 18) * 64;
    #pragma unroll
    for (int l = 0; l < 45; l++){
      int idx = tid + l*256;         // 180 c x 64 n
      int c = idx >> 6, nl = idx & 63;
      int n = n0 + nl;
      lds_f[nl*180 + c] = (n < 720) ? w1[(size_t)c*720 + n] : 0.f;
    }
    __syncthreads();
    u32* dst = (u32*)w1t;
    #pragma unroll
    for (int l = 0; l < 24; l++){
      int j = tid + l*256;           // 6144 u32 = 64 n x 96 cp
      int nl = j / 96, cp = j - nl*96;
      int c0 = 2*cp;
      float f0 = (c0   < 180) ? lds_f[nl*180 + c0]     : 0.f;
      float f1 = (c0+1 < 180) ? lds_f[nl*180 + c0 + 1] : 0.f;
      dst[(size_t)(n0 + nl)*96 + cp] = pack2(f0, f1);
    }
  } else {
    int c40 = (bid - 30) * 64;
    #pragma unroll
    for (int l = 0; l < 45; l++){
      int idx = tid + l*256;         // 64 c4 x 180 no
      int c4l = idx / 180, no = idx - c4l*180;
      lds_f[no*65 + c4l] = (c40 + c4l < 720) ? w2[(size_t)(c40 + c4l)*180 + no] : 0.f;
    }
    __syncthreads();
    u32* dst = (u32*)w2t;
    #pragma unroll
    for (int l = 0; l < 24; l++){
      int j = tid + l*256;           // 6144 u32 = 192 no x 32 cp
      int no = j >> 5, cp = j & 31;
      float f0 = (no < 180) ? lds_f[no*65 + 2*cp]     : 0.f;
      float f1 = (no < 180) ? lds_f[no*65 + 2*cp + 1] : 0.f;
      dst[(size_t)no*384 + (c40 >> 1) + cp] = pack2(f0, f1);
    }
  }
}

// ---------------- Fused kernel: 64 tokens (2 batches)/block, 4 waves, ~75KB LDS.
// W:   per-wave attn scratch -> act     (25.6KB)
// hn:  LN1 out -> x2 bf16 -> LN2 out    (25.6KB)
// att: attn out [t][c] contiguous       (23.5KB)
// x2 fp32 -> out (global, coalesced); MLP epilogue RMWs out.
// Global-load clusters fenced with sched_barrier(0) so they issue in flight together.
__global__ __launch_bounds__(256, 2)
void block_kernel(const float* __restrict__ x,
                  const float* __restrict__ g1, const float* __restrict__ be1,
                  const float* __restrict__ g2, const float* __restrict__ be2,
                  const float* __restrict__ b1, const float* __restrict__ b2,
                  const ushort_t* __restrict__ wqkv, const ushort_t* __restrict__ w1t,
                  const ushort_t* __restrict__ w2t, float* __restrict__ out){
  __shared__ __align__(16) ushort_t W[64*SH];
  __shared__ __align__(16) ushort_t hn[64*SH];
  __shared__ __align__(16) ushort_t att[64*SA];

  int tid = threadIdx.x;
  int wave = tid >> 6, lane = tid & 63;
  int quad = lane >> 4, c16 = lane & 15;
  long base = (long)blockIdx.x * 11520;   // 64 tokens * 180

  // ---- LN1 straight from global: 4 threads/row, 48 cols; loads clustered
  {
    int row = tid >> 2, sub = tid & 3;
    int c0 = sub*48;
    f32x4 xv[12];
    #pragma unroll
    for (int gi = 0; gi < 12; gi++){
      int c = c0 + gi*4;
      if (c < 180) xv[gi] = *(const f32x4*)(x + base + (long)row*180 + c);
      else         xv[gi] = (f32x4)0.f;
    }
    SBAR();
    float s1 = 0.f, s2 = 0.f;
    #pragma unroll
    for (int gi = 0; gi < 12; gi++){
      s1 += xv[gi].x + xv[gi].y + xv[gi].z + xv[gi].w;
      s2 += xv[gi].x*xv[gi].x + xv[gi].y*xv[gi].y + xv[gi].z*xv[gi].z + xv[gi].w*xv[gi].w;
    }
    s1 = red4_add(s1); s2 = red4_add(s2);
    float mu = s1 * (1.f/180.f);
    float rstd = rsqrtf(s2 * (1.f/180.f) - mu*mu + 1e-5f);
    #pragma unroll
    for (int gi = 0; gi < 12; gi++){
      int c = c0 + gi*4;
      if (c < 180){
        f32x4 gg = *(const f32x4*)(g1 + c);
        f32x4 bb = *(const f32x4*)(be1 + c);
        *(u64*)(hn + row*SH + c) = pack4((xv[gi].x - mu)*rstd*gg.x + bb.x,
                                         (xv[gi].y - mu)*rstd*gg.y + bb.y,
                                         (xv[gi].z - mu)*rstd*gg.z + bb.z,
                                         (xv[gi].w - mu)*rstd*gg.w + bb.w);
      } else {
        *(u64*)(hn + row*SH + c) = 0ull;
      }
    }
  }
  __syncthreads();

  // ---- attention: 12 jobs (2 batches x 6 heads), 3 per wave
  {
    ushort_t* buf0 = W + wave*(2*32*SS);   // q, then vT
    ushort_t* buf1 = buf0 + 32*SS;         // k, then P
    const float scl = 0.18257418583505537f;  // 30^-0.5

    for (int jj = 0; jj < 3; jj++){
      int j = wave*3 + jj;
      int bb = (j >= 6) ? 1 : 0;
      int head = j - 6*bb;
      const ushort_t* wbase = wqkv + head*(96*192);

      f32x4 accq[2][2], acck[2][2], accv[2][2];
      #pragma unroll
      for (int i = 0; i < 2; i++)
        #pragma unroll
        for (int jx = 0; jx < 2; jx++){ accq[i][jx]=(f32x4)0.f; acck[i][jx]=(f32x4)0.f; accv[i][jx]=(f32x4)0.f; }

      // preload wq/wk for ALL kk in one fenced cluster (24 loads in flight)
      short8 aqw[2][6], akw[2][6];
      #pragma unroll
      for (int mt = 0; mt < 2; mt++)
        #pragma unroll
        for (int kk = 0; kk < 6; kk++){
          aqw[mt][kk] = *(const short8*)(wbase + (      mt*16 + c16)*192 + kk*32 + quad*8);
          akw[mt][kk] = *(const short8*)(wbase + (32  + mt*16 + c16)*192 + kk*32 + quad*8);
          pin(aqw[mt][kk]); pin(akw[mt][kk]);
        }
      SBAR();
      // wv rotated 1-deep
      short8 avc[2], avn[2];
      #pragma unroll
      for (int mt = 0; mt < 2; mt++)
        avc[mt] = *(const short8*)(wbase + (64 + mt*16 + c16)*192 + quad*8);
      #pragma unroll
      for (int kk = 0; kk < 6; kk++){
        if (kk < 5){
          #pragma unroll
          for (int mt = 0; mt < 2; mt++)
            avn[mt] = *(const short8*)(wbase + (64 + mt*16 + c16)*192 + (kk+1)*32 + quad*8);
        }
        short8 hf[2];
        #pragma unroll
        for (int nt = 0; nt < 2; nt++)
          hf[nt] = *(const short8*)(hn + (bb*32 + nt*16 + c16)*SH + kk*32 + quad*8);
        #pragma unroll
        for (int mt = 0; mt < 2; mt++)
          #pragma unroll
          for (int nt = 0; nt < 2; nt++){
            accq[mt][nt] = MFMA16(aqw[mt][kk], hf[nt], accq[mt][nt]);  // C[d][t] = qT
            acck[mt][nt] = MFMA16(akw[mt][kk], hf[nt], acck[mt][nt]);  // C[d][t] = kT
            accv[mt][nt] = MFMA16(hf[mt], avc[nt], accv[mt][nt]);      // C[t][d] = v
          }
        if (kk < 5){
          #pragma unroll
          for (int mt = 0; mt < 2; mt++) avc[mt] = avn[mt];
        }
      }
      // q,k rowmajor [t][d] into scratch
      #pragma unroll
      for (int mt = 0; mt < 2; mt++)
        #pragma unroll
        for (int nt = 0; nt < 2; nt++){
          *(u64*)(buf0 + (nt*16 + c16)*SS + mt*16 + quad*4) =
            pack4(accq[mt][nt][0], accq[mt][nt][1], accq[mt][nt][2], accq[mt][nt][3]);
          *(u64*)(buf1 + (nt*16 + c16)*SS + mt*16 + quad*4) =
            pack4(acck[mt][nt][0], acck[mt][nt][1], acck[mt][nt][2], acck[mt][nt][3]);
        }
      // S^T = MFMA(A=k, B=q): C[s][t]
      f32x4 sacc[2][2];
      #pragma unroll
      for (int i = 0; i < 2; i++){ sacc[i][0]=(f32x4)0.f; sacc[i][1]=(f32x4)0.f; }
      short8 akf[2], bqf[2];
      #pragma unroll
      for (int mt = 0; mt < 2; mt++) akf[mt] = *(const short8*)(buf1 + (mt*16 + c16)*SS + quad*8);
      #pragma unroll
      for (int nt = 0; nt < 2; nt++) bqf[nt] = *(const short8*)(buf0 + (nt*16 + c16)*SS + quad*8);
      #pragma unroll
      for (int mt = 0; mt < 2; mt++)
        #pragma unroll
        for (int nt = 0; nt < 2; nt++)
          sacc[mt][nt] = MFMA16(akf[mt], bqf[nt], sacc[mt][nt]);
      // softmax: lane owns token t=nt*16+c16; reduce over quads (xor16,32)
      #pragma unroll
      for (int nt = 0; nt < 2; nt++){
        int t = nt*16 + c16;
        float v[8];
        #pragma unroll
        for (int r = 0; r < 4; r++){
          int s0 = quad*4 + r, s1v = 16 + quad*4 + r;
          v[r]   = (s0  > t) ? -1e30f : sacc[0][nt][r]*scl;
          v[4+r] = (s1v > t) ? -1e30f : sacc[1][nt][r]*scl;
        }
        float m = v[0];
        #pragma unroll
        for (int i = 1; i < 8; i++) m = fmaxf(m, v[i]);
        m = fmaxf(m, __shfl_xor(m, 16));
        m = fmaxf(m, __shfl_xor(m, 32));
        float e[8], s = 0.f;
        #pragma unroll
        for (int i = 0; i < 8; i++){ e[i] = __expf(v[i] - m); s += e[i]; }
        s += __shfl_xor(s, 16);
        s += __shfl_xor(s, 32);
        float inv = 1.f / s;
        *(u64*)(buf1 + t*SS +      quad*4) = pack4(e[0]*inv, e[1]*inv, e[2]*inv, e[3]*inv);
        *(u64*)(buf1 + t*SS + 16 + quad*4) = pack4(e[4]*inv, e[5]*inv, e[6]*inv, e[7]*inv);
      }
      // vT [d][t] into buf0 (q consumed)
      #pragma unroll
      for (int mt = 0; mt < 2; mt++)
        #pragma unroll
        for (int nt = 0; nt < 2; nt++)
          *(u64*)(buf0 + (nt*16 + c16)*SS + mt*16 + quad*4) =
            pack4(accv[mt][nt][0], accv[mt][nt][1], accv[mt][nt][2], accv[mt][nt][3]);
      // PV: C[d][t] = MFMA(A=vT, B=P) -> att[t][head*30+d] as u32 pairs
      f32x4 oacc[2][2];
      #pragma unroll
      for (int i = 0; i < 2; i++){ oacc[i][0]=(f32x4)0.f; oacc[i][1]=(f32x4)0.f; }
      short8 avf[2], bpf[2];
      #pragma unroll
      for (int mt = 0; mt < 2; mt++) avf[mt] = *(const short8*)(buf0 + (mt*16 + c16)*SS + quad*8);
      #pragma unroll
      for (int nt = 0; nt < 2; nt++) bpf[nt] = *(const short8*)(buf1 + (nt*16 + c16)*SS + quad*8);
      #pragma unroll
      for (int mt = 0; mt < 2; mt++)
        #pragma unroll
        for (int nt = 0; nt < 2; nt++)
          oacc[mt][nt] = MFMA16(avf[mt], bpf[nt], oacc[mt][nt]);
      // write: lane holds d = mt*16 + quad*4 + r for token t=nt*16+c16
      #pragma unroll
      for (int mt = 0; mt < 2; mt++)
        #pragma unroll
        for (int nt = 0; nt < 2; nt++){
          int t = bb*32 + nt*16 + c16;
          int c = head*30 + mt*16 + quad*4;    // even -> u32 aligned
          ushort_t* p = att + t*SA + c;
          *(u32*)(p) = pack2(oacc[mt][nt][0], oacc[mt][nt][1]);
          if (mt == 0 || quad < 3)
            *(u32*)(p + 2) = pack2(oacc[mt][nt][2], oacc[mt][nt][3]);
        }
    }
  }
  __syncthreads();

  // ---- x2 = x + att: fp32 -> out (coalesced), bf16 -> hn ; x loads clustered
  {
    f32x4 xv2[12];
    #pragma unroll
    for (int it = 0; it < 12; it++){
      int idx = it*256 + tid;
      if (idx < 2880) xv2[it] = *(const f32x4*)(x + base + (long)idx*4);
    }
    SBAR();
    #pragma unroll
    for (int it = 0; it < 12; it++){
      int idx = it*256 + tid;
      if (idx < 2880){
        f32x4 v = xv2[it];
        int row = (int)(((u32)idx * 745655u) >> 25);   // idx/45
        int col4 = (idx - row*45)*4;
        u64 m = *(const u64*)(att + row*SA + col4);
        v.x += bf2f((ushort_t)(m      ));
        v.y += bf2f((ushort_t)(m >> 16));
        v.z += bf2f((ushort_t)(m >> 32));
        v.w += bf2f((ushort_t)(m >> 48));
        *(f32x4*)(out + base + (long)idx*4) = v;                 // x2 fp32
        *(u64*)(hn + row*SH + col4) = pack4(v.x, v.y, v.z, v.w); // x2 bf16
      } else {
        int p = idx - 2880;
        int row = (p*21846) >> 16;
        int g = p - row*3;
        *(u64*)(hn + row*SH + 180 + g*4) = 0ull;
      }
    }
  }
  __syncthreads();

  // ---- LN2 in-place on hn
  {
    int row = tid >> 2, sub = tid & 3;
    int c0 = sub*48;
    float s1 = 0.f, s2 = 0.f;
    u64 mv[12];
    #pragma unroll
    for (int gi = 0; gi < 12; gi++){
      mv[gi] = *(const u64*)(hn + row*SH + c0 + gi*4);
      #pragma unroll
      for (int e = 0; e < 4; e++){
        float v = bf2f((ushort_t)(mv[gi] >> (16*e)));
        s1 += v; s2 += v*v;
      }
    }
    s1 = red4_add(s1); s2 = red4_add(s2);
    float mu = s1 * (1.f/180.f);
    float rstd = rsqrtf(s2 * (1.f/180.f) - mu*mu + 1e-5f);
    #pragma unroll
    for (int gi = 0; gi < 12; gi++){
      int c = c0 + gi*4;
      if (c < 180){
        f32x4 gg = *(const f32x4*)(g2 + c);
        f32x4 bb = *(const f32x4*)(be2 + c);
        float v0 = (bf2f((ushort_t)(mv[gi]    )) - mu)*rstd*gg.x + bb.x;
        float v1 = (bf2f((ushort_t)(mv[gi]>>16)) - mu)*rstd*gg.y + bb.y;
        float v2 = (bf2f((ushort_t)(mv[gi]>>32)) - mu)*rstd*gg.z + bb.z;
        float v3 = (bf2f((ushort_t)(mv[gi]>>48)) - mu)*rstd*gg.w + bb.w;
        *(u64*)(hn + row*SH + c) = pack4(v0, v1, v2, v3);
      }
    }
  }
  __syncthreads();

  // ---- MLP: 4 chunks of 192 hidden; act overlays W
  {
    ushort_t* act = W;
    f32x4 outacc[4][3];   // [t-tile][no-tile]
    #pragma unroll
    for (int i = 0; i < 4; i++)
      #pragma unroll
      for (int jx = 0; jx < 3; jx++) outacc[i][jx] = (f32x4)0.f;

    for (int ch = 0; ch < 4; ch++){
      // MLP1: C[n][t] = MFMA(A=w1 rows n, B=hn rows t); w1 preloaded, fenced
      f32x4 aacc[3][4];
      #pragma unroll
      for (int i = 0; i < 3; i++)
        #pragma unroll
        for (int jx = 0; jx < 4; jx++) aacc[i][jx] = (f32x4)0.f;
      short8 aw[3][6];
      #pragma unroll
      for (int mi = 0; mi < 3; mi++)
        #pragma unroll
        for (int kk = 0; kk < 6; kk++){
          aw[mi][kk] = *(const short8*)(w1t + (size_t)(ch*192 + (wave*3+mi)*16 + c16)*192 + kk*32 + quad*8);
          pin(aw[mi][kk]);
        }
      SBAR();
      #pragma unroll
      for (int kk = 0; kk < 6; kk++){
        short8 bh[4];
        #pragma unroll
        for (int tt = 0; tt < 4; tt++)
          bh[tt] = *(const short8*)(hn + (tt*16 + c16)*SH + kk*32 + quad*8);
        #pragma unroll
        for (int mi = 0; mi < 3; mi++)
          #pragma unroll
          for (int tt = 0; tt < 4; tt++)
            aacc[mi][tt] = MFMA16(aw[mi][kk], bh[tt], aacc[mi][tt]);
      }
      __syncthreads();   // prev chunk's MLP2 done reading act
      // bias + relu + packed store act[t][n]
      #pragma unroll
      for (int mi = 0; mi < 3; mi++){
        int nrel = (wave*3+mi)*16 + quad*4;
        int nabs = ch*192 + nrel;
        f32x4 bias = (f32x4)0.f;
        if (nabs < 720) bias = *(const f32x4*)(b1 + nabs);
        #pragma unroll
        for (int tt = 0; tt < 4; tt++){
          float v0 = fmaxf(aacc[mi][tt][0] + bias[0], 0.f);
          float v1 = fmaxf(aacc[mi][tt][1] + bias[1], 0.f);
          float v2 = fmaxf(aacc[mi][tt][2] + bias[2], 0.f);
          float v3 = fmaxf(aacc[mi][tt][3] + bias[3], 0.f);
          *(u64*)(act + (tt*16 + c16)*SH + nrel) = pack4(v0, v1, v2, v3);
        }
      }
      __syncthreads();   // act ready
      // MLP2: C[t][no] += MFMA(A=act rows t, B=w2 rows no); w2 preloaded, fenced
      short8 bw[3][6];
      #pragma unroll
      for (int ntl = 0; ntl < 3; ntl++)
        #pragma unroll
        for (int kk = 0; kk < 6; kk++){
          bw[ntl][kk] = *(const short8*)(w2t + (size_t)(wave*48 + ntl*16 + c16)*768 + ch*192 + kk*32 + quad*8);
          pin(bw[ntl][kk]);
        }
      SBAR();
      #pragma unroll
      for (int kk = 0; kk < 6; kk++){
        short8 aa[4];
        #pragma unroll
        for (int tt = 0; tt < 4; tt++)
          aa[tt] = *(const short8*)(act + (tt*16 + c16)*SH + kk*32 + quad*8);
        #pragma unroll
        for (int tt = 0; tt < 4; tt++)
          #pragma unroll
          for (int ntl = 0; ntl < 3; ntl++)
            outacc[tt][ntl] = MFMA16(aa[tt], bw[ntl][kk], outacc[tt][ntl]);
      }
    }
    // epilogue: out[t][no] = x2 (already in out) + mlp + b2
    #pragma unroll
    for (int ntl = 0; ntl < 3; ntl++){
      int no = wave*48 + ntl*16 + c16;
      if (no < 180){
        float bias = b2[no];
        #pragma unroll
        for (int tt = 0; tt < 4; tt++){
          #pragma unroll
          for (int r = 0; r < 4; r++){
            long a = base + (long)(tt*16 + quad*4 + r)*180 + no;
            out[a] = out[a] + outacc[tt][ntl][r] + bias;
          }
        }
      }
    }
  }
}

extern "C" void kernel_launch(void* const* d_in, const int* in_sizes, int n_in,
                              void* d_out, int out_size, void* d_ws, size_t ws_size,
                              hipStream_t stream) {
  const float* x   = (const float*)d_in[0];
  const float* wq  = (const float*)d_in[1];
  const float* wk  = (const float*)d_in[2];
  const float* wv  = (const float*)d_in[3];
  const float* g1  = (const float*)d_in[4];
  const float* be1 = (const float*)d_in[5];
  const float* g2  = (const float*)d_in[6];
  const float* be2 = (const float*)d_in[7];
  const float* w1  = (const float*)d_in[8];
  const float* b1  = (const float*)d_in[9];
  const float* w2  = (const float*)d_in[10];
  const float* b2  = (const float*)d_in[11];
  ushort_t* ws   = (ushort_t*)d_ws;
  ushort_t* wqkv = ws;
  ushort_t* w1t  = ws + WQKV_ELEMS;
  ushort_t* w2t  = w1t + W1T_ELEMS;
  float* out = (float*)d_out;

  prep_weights<<<42, 256, 0, stream>>>(wq, wk, wv, w1, w2, ws);
  block_kernel<<<2048, 256, 0, stream>>>(x, g1, be1, g2, be2, b1, b2,
                                         wqkv, w1t, w2t, out);
}

// Round 7
// 513.768 us; speedup vs baseline: 1.1464x; 1.0044x over previous
//
#include <hip/hip_runtime.h>

typedef __attribute__((ext_vector_type(8))) short short8;
typedef __attribute__((ext_vector_type(4))) float f32x4;
typedef unsigned short ushort_t;
typedef unsigned int u32;
typedef unsigned long long u64;

#define MFMA16(a,b,c) __builtin_amdgcn_mfma_f32_16x16x32_bf16((a),(b),(c),0,0,0)

__device__ __forceinline__ ushort_t f2bf(float f){
  union { float f; u32 u; } v; v.f = f;
  u32 r = v.u + 0x7fffu + ((v.u >> 16) & 1u);
  return (ushort_t)(r >> 16);
}
__device__ __forceinline__ float bf2f(ushort_t h){
  union { u32 u; float f; } v; v.u = ((u32)h) << 16; return v.f;
}
__device__ __forceinline__ u64 pack4(float a, float b, float c, float d){
  u32 p0 = (u32)f2bf(a) | ((u32)f2bf(b) << 16);
  u32 p1 = (u32)f2bf(c) | ((u32)f2bf(d) << 16);
  return (u64)p0 | ((u64)p1 << 32);
}
__device__ __forceinline__ u32 pack2(float a, float b){
  return (u32)f2bf(a) | ((u32)f2bf(b) << 16);
}

template<int CTRL>
__device__ __forceinline__ float dpp_add(float x){
  union { float f; int i; } a, b;
  a.f = x;
  b.i = __builtin_amdgcn_update_dpp(a.i, a.i, CTRL, 0xF, 0xF, false);
  return x + b.f;
}
__device__ __forceinline__ float red4_add(float x){
  x = dpp_add<0xB1>(x); x = dpp_add<0x4E>(x);
  return x;
}

// B=4096 T=32 C=180 H=6 HD=30 ; tokens=131072
// ws (ushort): wqkv[6][3][32][192] | w1t[768][192] | w2t[192][768]
#define WQKV_ELEMS (576*192)
#define W1T_ELEMS  (768*192)
#define W2T_ELEMS  (192*768)

#define SH 200   // 400B rows (192 cols + pad)
#define SS 40    //  80B rows: attn scratch
#define SA 184   // att rows [t][c] c=head*30+d (180 + 4 pad)

// ---- prep: LDS-tiled coalesced transposes (runs once, 42 blocks)
__global__ void prep_weights(const float* __restrict__ wq, const float* __restrict__ wk,
                             const float* __restrict__ wv, const float* __restrict__ w1,
                             const float* __restrict__ w2, ushort_t* __restrict__ ws){
  __shared__ float lds_f[11700];
  ushort_t* wqkv = ws;
  ushort_t* w1t = ws + WQKV_ELEMS;
  ushort_t* w2t = w1t + W1T_ELEMS;
  int bid = blockIdx.x, tid = threadIdx.x;

  if (bid < 18){
    int h = bid / 3, m = bid % 3;
    const float* src = ((m == 0) ? wq : (m == 1) ? wk : wv) + (size_t)h*180*30;
    for (int l = 0; l < 22; l++){
      int idx = tid + l*256;
      if (idx < 5400) lds_f[idx] = src[idx];
    }
    __syncthreads();
    u32* dst = (u32*)wqkv;
    for (int l = 0; l < 12; l++){
      int j = tid + l*256;
      int d = j / 96, kp = j - d*96;
      int k0 = 2*kp;
      float f0 = (d < 30 && k0   < 180) ? lds_f[k0*30 + d]     : 0.f;
      float f1 = (d < 30 && k0+1 < 180) ? lds_f[(k0+1)*30 + d] : 0.f;
      dst[(size_t)(h*96 + m*32 + d)*96 + kp] = pack2(f0, f1);
    }
  } else if (bid < 30){
    int n0 = (bid - 18) * 64;
    for (int l = 0; l < 45; l++){
      int idx = tid + l*256;
      int c = idx >> 6, nl = idx & 63;
      int n = n0 + nl;
      lds_f[nl*180 + c] = (n < 720) ? w1[(size_t)c*720 + n] : 0.f;
    }
    __syncthreads();
    u32* dst = (u32*)w1t;
    for (int l = 0; l < 24; l++){
      int j = tid + l*256;
      int nl = j / 96, cp = j - nl*96;
      int c0 = 2*cp;
      float f0 = (c0   < 180) ? lds_f[nl*180 + c0]     : 0.f;
      float f1 = (c0+1 < 180) ? lds_f[nl*180 + c0 + 1] : 0.f;
      dst[(size_t)(n0 + nl)*96 + cp] = pack2(f0, f1);
    }
  } else {
    int c40 = (bid - 30) * 64;
    for (int l = 0; l < 45; l++){
      int idx = tid + l*256;
      int c4l = idx / 180, no = idx - c4l*180;
      lds_f[no*65 + c4l] = (c40 + c4l < 720) ? w2[(size_t)(c40 + c4l)*180 + no] : 0.f;
    }
    __syncthreads();
    u32* dst = (u32*)w2t;
    for (int l = 0; l < 24; l++){
      int j = tid + l*256;
      int no = j >> 5, cp = j & 31;
      float f0 = (no < 180) ? lds_f[no*65 + 2*cp]     : 0.f;
      float f1 = (no < 180) ? lds_f[no*65 + 2*cp + 1] : 0.f;
      dst[(size_t)no*384 + (c40 >> 1) + cp] = pack2(f0, f1);
    }
  }
}

// ---------------- Fused kernel: 64 tokens/block, 4 waves, 74.75KB LDS, 2 blocks/CU.
// CODE-SIZE-MINIMAL: all phase loops rolled (#pragma unroll 1) so the text fits the
// 32KB I-cache — per-block cost was ~220K cy independent of work = I-fetch streaming.
__global__ __launch_bounds__(256, 2)
void block_kernel(const float* __restrict__ x,
                  const float* __restrict__ g1, const float* __restrict__ be1,
                  const float* __restrict__ g2, const float* __restrict__ be2,
                  const float* __restrict__ b1, const float* __restrict__ b2,
                  const ushort_t* __restrict__ wqkv, const ushort_t* __restrict__ w1t,
                  const ushort_t* __restrict__ w2t, float* __restrict__ out){
  __shared__ __align__(16) ushort_t W[64*SH];    // attn scratch -> act
  __shared__ __align__(16) ushort_t hn[64*SH];   // x bf16 -> LN1 -> x2 -> LN2
  __shared__ __align__(16) ushort_t att[64*SA];  // attn out [t][c]

  int tid = threadIdx.x;
  int wave = tid >> 6, lane = tid & 63;
  int quad = lane >> 4, c16 = lane & 15;
  long base = (long)blockIdx.x * 11520;   // 64 tokens * 180

  // ---- stage x -> hn bf16 (pad cols 180..191 zero)
  #pragma unroll 1
  for (int it = 0; it < 12; it++){
    int idx = it*256 + tid;
    if (idx < 2880){
      f32x4 v = *(const f32x4*)(x + base + (long)idx*4);
      int row = (int)(((u32)idx * 745655u) >> 25);   // idx/45
      int col = idx - row*45;
      *(u64*)(hn + row*SH + col*4) = pack4(v.x, v.y, v.z, v.w);
    } else {
      int p = idx - 2880;
      int row = (p*21846) >> 16;
      int g = p - row*3;
      *(u64*)(hn + row*SH + 180 + g*4) = 0ull;
    }
  }
  __syncthreads();

  // ---- LN1 in-place on hn (4 threads/row, 48 cols each; pad zeros included)
  {
    int row = tid >> 2, sub = tid & 3;
    int c0 = sub*48;
    float s1 = 0.f, s2 = 0.f;
    u64 mv[12];
    #pragma unroll
    for (int gi = 0; gi < 12; gi++){
      mv[gi] = *(const u64*)(hn + row*SH + c0 + gi*4);
      #pragma unroll
      for (int e = 0; e < 4; e++){
        float v = bf2f((ushort_t)(mv[gi] >> (16*e)));
        s1 += v; s2 += v*v;
      }
    }
    s1 = red4_add(s1); s2 = red4_add(s2);
    float mu = s1 * (1.f/180.f);
    float rstd = rsqrtf(s2 * (1.f/180.f) - mu*mu + 1e-5f);
    #pragma unroll
    for (int gi = 0; gi < 12; gi++){
      int c = c0 + gi*4;
      if (c < 180){
        f32x4 gg = *(const f32x4*)(g1 + c);
        f32x4 bb = *(const f32x4*)(be1 + c);
        float v0 = (bf2f((ushort_t)(mv[gi]    )) - mu)*rstd*gg.x + bb.x;
        float v1 = (bf2f((ushort_t)(mv[gi]>>16)) - mu)*rstd*gg.y + bb.y;
        float v2 = (bf2f((ushort_t)(mv[gi]>>32)) - mu)*rstd*gg.z + bb.z;
        float v3 = (bf2f((ushort_t)(mv[gi]>>48)) - mu)*rstd*gg.w + bb.w;
        *(u64*)(hn + row*SH + c) = pack4(v0, v1, v2, v3);
      }
    }
  }
  __syncthreads();

  // ---- attention: 12 jobs (2 batches x 6 heads), 3 per wave; jj and kk ROLLED
  {
    ushort_t* buf0 = W + wave*(2*32*SS);   // q, then vT
    ushort_t* buf1 = buf0 + 32*SS;         // k, then P
    const float scl = 0.18257418583505537f;  // 30^-0.5

    #pragma unroll 1
    for (int jj = 0; jj < 3; jj++){
      int j = wave*3 + jj;
      int bb = (j >= 6) ? 1 : 0;
      int head = j - 6*bb;
      const ushort_t* wbase = wqkv + head*(96*192);

      f32x4 accq[2][2], acck[2][2], accv[2][2];
      #pragma unroll
      for (int i = 0; i < 2; i++)
        #pragma unroll
        for (int jx = 0; jx < 2; jx++){ accq[i][jx]=(f32x4)0.f; acck[i][jx]=(f32x4)0.f; accv[i][jx]=(f32x4)0.f; }

      #pragma unroll 1
      for (int kk = 0; kk < 6; kk++){
        const ushort_t* wk0 = wbase + c16*192 + kk*32 + quad*8;
        short8 aq0 = *(const short8*)(wk0);
        short8 aq1 = *(const short8*)(wk0 + 16*192);
        short8 ak0 = *(const short8*)(wk0 + 32*192);
        short8 ak1 = *(const short8*)(wk0 + 48*192);
        short8 av0 = *(const short8*)(wk0 + 64*192);
        short8 av1 = *(const short8*)(wk0 + 80*192);
        const ushort_t* hb = hn + (bb*32 + c16)*SH + kk*32 + quad*8;
        short8 hf0 = *(const short8*)(hb);
        short8 hf1 = *(const short8*)(hb + 16*SH);
        accq[0][0] = MFMA16(aq0, hf0, accq[0][0]);
        accq[0][1] = MFMA16(aq0, hf1, accq[0][1]);
        accq[1][0] = MFMA16(aq1, hf0, accq[1][0]);
        accq[1][1] = MFMA16(aq1, hf1, accq[1][1]);
        acck[0][0] = MFMA16(ak0, hf0, acck[0][0]);
        acck[0][1] = MFMA16(ak0, hf1, acck[0][1]);
        acck[1][0] = MFMA16(ak1, hf0, acck[1][0]);
        acck[1][1] = MFMA16(ak1, hf1, acck[1][1]);
        accv[0][0] = MFMA16(hf0, av0, accv[0][0]);
        accv[0][1] = MFMA16(hf0, av1, accv[0][1]);
        accv[1][0] = MFMA16(hf1, av0, accv[1][0]);
        accv[1][1] = MFMA16(hf1, av1, accv[1][1]);
      }
      // q,k rowmajor [t][d] into scratch
      #pragma unroll
      for (int mt = 0; mt < 2; mt++)
        #pragma unroll
        for (int nt = 0; nt < 2; nt++){
          *(u64*)(buf0 + (nt*16 + c16)*SS + mt*16 + quad*4) =
            pack4(accq[mt][nt][0], accq[mt][nt][1], accq[mt][nt][2], accq[mt][nt][3]);
          *(u64*)(buf1 + (nt*16 + c16)*SS + mt*16 + quad*4) =
            pack4(acck[mt][nt][0], acck[mt][nt][1], acck[mt][nt][2], acck[mt][nt][3]);
        }
      // S^T = MFMA(A=k, B=q): C[s][t]
      f32x4 sacc[2][2];
      #pragma unroll
      for (int i = 0; i < 2; i++){ sacc[i][0]=(f32x4)0.f; sacc[i][1]=(f32x4)0.f; }
      short8 akf[2], bqf[2];
      #pragma unroll
      for (int mt = 0; mt < 2; mt++) akf[mt] = *(const short8*)(buf1 + (mt*16 + c16)*SS + quad*8);
      #pragma unroll
      for (int nt = 0; nt < 2; nt++) bqf[nt] = *(const short8*)(buf0 + (nt*16 + c16)*SS + quad*8);
      #pragma unroll
      for (int mt = 0; mt < 2; mt++)
        #pragma unroll
        for (int nt = 0; nt < 2; nt++)
          sacc[mt][nt] = MFMA16(akf[mt], bqf[nt], sacc[mt][nt]);
      // softmax
      #pragma unroll
      for (int nt = 0; nt < 2; nt++){
        int t = nt*16 + c16;
        float v[8];
        #pragma unroll
        for (int r = 0; r < 4; r++){
          int s0 = quad*4 + r, s1v = 16 + quad*4 + r;
          v[r]   = (s0  > t) ? -1e30f : sacc[0][nt][r]*scl;
          v[4+r] = (s1v > t) ? -1e30f : sacc[1][nt][r]*scl;
        }
        float m = v[0];
        #pragma unroll
        for (int i = 1; i < 8; i++) m = fmaxf(m, v[i]);
        m = fmaxf(m, __shfl_xor(m, 16));
        m = fmaxf(m, __shfl_xor(m, 32));
        float e[8], s = 0.f;
        #pragma unroll
        for (int i = 0; i < 8; i++){ e[i] = __expf(v[i] - m); s += e[i]; }
        s += __shfl_xor(s, 16);
        s += __shfl_xor(s, 32);
        float inv = 1.f / s;
        *(u64*)(buf1 + t*SS +      quad*4) = pack4(e[0]*inv, e[1]*inv, e[2]*inv, e[3]*inv);
        *(u64*)(buf1 + t*SS + 16 + quad*4) = pack4(e[4]*inv, e[5]*inv, e[6]*inv, e[7]*inv);
      }
      // vT [d][t] into buf0 (q consumed)
      #pragma unroll
      for (int mt = 0; mt < 2; mt++)
        #pragma unroll
        for (int nt = 0; nt < 2; nt++)
          *(u64*)(buf0 + (nt*16 + c16)*SS + mt*16 + quad*4) =
            pack4(accv[mt][nt][0], accv[mt][nt][1], accv[mt][nt][2], accv[mt][nt][3]);
      // PV: C[d][t] = MFMA(A=vT, B=P) -> att[t][head*30+d] u32 pairs
      f32x4 oacc[2][2];
      #pragma unroll
      for (int i = 0; i < 2; i++){ oacc[i][0]=(f32x4)0.f; oacc[i][1]=(f32x4)0.f; }
      short8 avf[2], bpf[2];
      #pragma unroll
      for (int mt = 0; mt < 2; mt++) avf[mt] = *(const short8*)(buf0 + (mt*16 + c16)*SS + quad*8);
      #pragma unroll
      for (int nt = 0; nt < 2; nt++) bpf[nt] = *(const short8*)(buf1 + (nt*16 + c16)*SS + quad*8);
      #pragma unroll
      for (int mt = 0; mt < 2; mt++)
        #pragma unroll
        for (int nt = 0; nt < 2; nt++)
          oacc[mt][nt] = MFMA16(avf[mt], bpf[nt], oacc[mt][nt]);
      #pragma unroll
      for (int mt = 0; mt < 2; mt++)
        #pragma unroll
        for (int nt = 0; nt < 2; nt++){
          int t = bb*32 + nt*16 + c16;
          int c = head*30 + mt*16 + quad*4;
          ushort_t* p = att + t*SA + c;
          *(u32*)(p) = pack2(oacc[mt][nt][0], oacc[mt][nt][1]);
          if (mt == 0 || quad < 3)
            *(u32*)(p + 2) = pack2(oacc[mt][nt][2], oacc[mt][nt][3]);
        }
    }
  }
  __syncthreads();

  // ---- x2 = x + att: fp32 -> out (coalesced), bf16 -> hn
  #pragma unroll 1
  for (int it = 0; it < 12; it++){
    int idx = it*256 + tid;
    if (idx < 2880){
      f32x4 v = *(const f32x4*)(x + base + (long)idx*4);
      int row = (int)(((u32)idx * 745655u) >> 25);
      int col4 = (idx - row*45)*4;
      u64 m = *(const u64*)(att + row*SA + col4);
      v.x += bf2f((ushort_t)(m      ));
      v.y += bf2f((ushort_t)(m >> 16));
      v.z += bf2f((ushort_t)(m >> 32));
      v.w += bf2f((ushort_t)(m >> 48));
      *(f32x4*)(out + base + (long)idx*4) = v;
      *(u64*)(hn + row*SH + col4) = pack4(v.x, v.y, v.z, v.w);
    }
    // pad cols in hn still zero from the stage phase
  }
  __syncthreads();

  // ---- LN2 in-place on hn
  {
    int row = tid >> 2, sub = tid & 3;
    int c0 = sub*48;
    float s1 = 0.f, s2 = 0.f;
    u64 mv[12];
    #pragma unroll
    for (int gi = 0; gi < 12; gi++){
      mv[gi] = *(const u64*)(hn + row*SH + c0 + gi*4);
      #pragma unroll
      for (int e = 0; e < 4; e++){
        float v = bf2f((ushort_t)(mv[gi] >> (16*e)));
        s1 += v; s2 += v*v;
      }
    }
    s1 = red4_add(s1); s2 = red4_add(s2);
    float mu = s1 * (1.f/180.f);
    float rstd = rsqrtf(s2 * (1.f/180.f) - mu*mu + 1e-5f);
    #pragma unroll
    for (int gi = 0; gi < 12; gi++){
      int c = c0 + gi*4;
      if (c < 180){
        f32x4 gg = *(const f32x4*)(g2 + c);
        f32x4 bb = *(const f32x4*)(be2 + c);
        float v0 = (bf2f((ushort_t)(mv[gi]    )) - mu)*rstd*gg.x + bb.x;
        float v1 = (bf2f((ushort_t)(mv[gi]>>16)) - mu)*rstd*gg.y + bb.y;
        float v2 = (bf2f((ushort_t)(mv[gi]>>32)) - mu)*rstd*gg.z + bb.z;
        float v3 = (bf2f((ushort_t)(mv[gi]>>48)) - mu)*rstd*gg.w + bb.w;
        *(u64*)(hn + row*SH + c) = pack4(v0, v1, v2, v3);
      }
    }
  }
  __syncthreads();

  // ---- MLP: ch ROLLED x4; kk ROLLED x6 with in-loop loads; act overlays W
  {
    ushort_t* act = W;
    f32x4 outacc[4][3];
    #pragma unroll
    for (int i = 0; i < 4; i++)
      #pragma unroll
      for (int jx = 0; jx < 3; jx++) outacc[i][jx] = (f32x4)0.f;

    #pragma unroll 1
    for (int ch = 0; ch < 4; ch++){
      f32x4 aacc[3][4];
      #pragma unroll
      for (int i = 0; i < 3; i++)
        #pragma unroll
        for (int jx = 0; jx < 4; jx++) aacc[i][jx] = (f32x4)0.f;
      // MLP1: C[n][t] = MFMA(A=w1 rows n, B=hn rows t)
      #pragma unroll 1
      for (int kk = 0; kk < 6; kk++){
        const ushort_t* wb = w1t + (size_t)(ch*192 + wave*48 + c16)*192 + kk*32 + quad*8;
        short8 aw0 = *(const short8*)(wb);
        short8 aw1 = *(const short8*)(wb + 16*192);
        short8 aw2 = *(const short8*)(wb + 32*192);
        const ushort_t* hb = hn + c16*SH + kk*32 + quad*8;
        short8 bh0 = *(const short8*)(hb);
        short8 bh1 = *(const short8*)(hb + 16*SH);
        short8 bh2 = *(const short8*)(hb + 32*SH);
        short8 bh3 = *(const short8*)(hb + 48*SH);
        aacc[0][0] = MFMA16(aw0, bh0, aacc[0][0]);
        aacc[0][1] = MFMA16(aw0, bh1, aacc[0][1]);
        aacc[0][2] = MFMA16(aw0, bh2, aacc[0][2]);
        aacc[0][3] = MFMA16(aw0, bh3, aacc[0][3]);
        aacc[1][0] = MFMA16(aw1, bh0, aacc[1][0]);
        aacc[1][1] = MFMA16(aw1, bh1, aacc[1][1]);
        aacc[1][2] = MFMA16(aw1, bh2, aacc[1][2]);
        aacc[1][3] = MFMA16(aw1, bh3, aacc[1][3]);
        aacc[2][0] = MFMA16(aw2, bh0, aacc[2][0]);
        aacc[2][1] = MFMA16(aw2, bh1, aacc[2][1]);
        aacc[2][2] = MFMA16(aw2, bh2, aacc[2][2]);
        aacc[2][3] = MFMA16(aw2, bh3, aacc[2][3]);
      }
      __syncthreads();   // prev chunk's MLP2 done reading act
      // bias + relu + packed store act[t][n]
      #pragma unroll
      for (int mi = 0; mi < 3; mi++){
        int nrel = (wave*3+mi)*16 + quad*4;
        int nabs = ch*192 + nrel;
        f32x4 bias = (f32x4)0.f;
        if (nabs < 720) bias = *(const f32x4*)(b1 + nabs);
        #pragma unroll
        for (int tt = 0; tt < 4; tt++){
          float v0 = fmaxf(aacc[mi][tt][0] + bias[0], 0.f);
          float v1 = fmaxf(aacc[mi][tt][1] + bias[1], 0.f);
          float v2 = fmaxf(aacc[mi][tt][2] + bias[2], 0.f);
          float v3 = fmaxf(aacc[mi][tt][3] + bias[3], 0.f);
          *(u64*)(act + (tt*16 + c16)*SH + nrel) = pack4(v0, v1, v2, v3);
        }
      }
      __syncthreads();   // act ready
      // MLP2: C[t][no] += MFMA(A=act rows t, B=w2 rows no)
      #pragma unroll 1
      for (int kk = 0; kk < 6; kk++){
        const ushort_t* wb = w2t + (size_t)(wave*48 + c16)*768 + ch*192 + kk*32 + quad*8;
        short8 bw0 = *(const short8*)(wb);
        short8 bw1 = *(const short8*)(wb + 16*768);
        short8 bw2 = *(const short8*)(wb + 32*768);
        const ushort_t* ab = act + c16*SH + kk*32 + quad*8;
        short8 aa0 = *(const short8*)(ab);
        short8 aa1 = *(const short8*)(ab + 16*SH);
        short8 aa2 = *(const short8*)(ab + 32*SH);
        short8 aa3 = *(const short8*)(ab + 48*SH);
        outacc[0][0] = MFMA16(aa0, bw0, outacc[0][0]);
        outacc[0][1] = MFMA16(aa0, bw1, outacc[0][1]);
        outacc[0][2] = MFMA16(aa0, bw2, outacc[0][2]);
        outacc[1][0] = MFMA16(aa1, bw0, outacc[1][0]);
        outacc[1][1] = MFMA16(aa1, bw1, outacc[1][1]);
        outacc[1][2] = MFMA16(aa1, bw2, outacc[1][2]);
        outacc[2][0] = MFMA16(aa2, bw0, outacc[2][0]);
        outacc[2][1] = MFMA16(aa2, bw1, outacc[2][1]);
        outacc[2][2] = MFMA16(aa2, bw2, outacc[2][2]);
        outacc[3][0] = MFMA16(aa3, bw0, outacc[3][0]);
        outacc[3][1] = MFMA16(aa3, bw1, outacc[3][1]);
        outacc[3][2] = MFMA16(aa3, bw2, outacc[3][2]);
      }
    }
    // epilogue: out[t][no] = x2 (already in out) + mlp + b2
    #pragma unroll
    for (int ntl = 0; ntl < 3; ntl++){
      int no = wave*48 + ntl*16 + c16;
      if (no < 180){
        float bias = b2[no];
        #pragma unroll
        for (int tt = 0; tt < 4; tt++){
          #pragma unroll
          for (int r = 0; r < 4; r++){
            long a = base + (long)(tt*16 + quad*4 + r)*180 + no;
            out[a] = out[a] + outacc[tt][ntl][r] + bias;
          }
        }
      }
    }
  }
}

extern "C" void kernel_launch(void* const* d_in, const int* in_sizes, int n_in,
                              void* d_out, int out_size, void* d_ws, size_t ws_size,
                              hipStream_t stream) {
  const float* x   = (const float*)d_in[0];
  const float* wq  = (const float*)d_in[1];
  const float* wk  = (const float*)d_in[2];
  const float* wv  = (const float*)d_in[3];
  const float* g1  = (const float*)d_in[4];
  const float* be1 = (const float*)d_in[5];
  const float* g2  = (const float*)d_in[6];
  const float* be2 = (const float*)d_in[7];
  const float* w1  = (const float*)d_in[8];
  const float* b1  = (const float*)d_in[9];
  const float* w2  = (const float*)d_in[10];
  const float* b2  = (const float*)d_in[11];
  ushort_t* ws   = (ushort_t*)d_ws;
  ushort_t* wqkv = ws;
  ushort_t* w1t  = ws + WQKV_ELEMS;
  ushort_t* w2t  = w1t + W1T_ELEMS;
  float* out = (float*)d_out;

  prep_weights<<<42, 256, 0, stream>>>(wq, wk, wv, w1, w2, ws);
  block_kernel<<<2048, 256, 0, stream>>>(x, g1, be1, g2, be2, b1, b2,
                                         wqkv, w1t, w2t, out);
}